// Round 20
// baseline (208.879 us; speedup 1.0000x reference)
//
#include <hip/hip_runtime.h>
#include <hip/hip_bf16.h>

typedef __bf16 bf16_t;
typedef __bf16 bf16x8 __attribute__((ext_vector_type(8)));
typedef __bf16 bf16x4 __attribute__((ext_vector_type(4)));
typedef float f32x4 __attribute__((ext_vector_type(4)));

#define N_TOK 343
#define NP    352
#define DIM   192
#define HEADS 6
#define HD    32
#define BATCH 256
#define NW    64
#define MROWS (BATCH * N_TOK)   /* 87808 = 1372 * 64 */
#define LOG2E 1.4426950408889634f

/* prep task-space segmentation */
#define WB_TASKS   18432                      /* 4 mats x 4608 8-chunks */
#define MROW_CH    44                         /* 352/8 chunks per row */
#define MASK_TASKS (NW * N_TOK * MROW_CH)     /* 965,888 */
#define BIAS_TASKS (HEADS * N_TOK * MROW_CH)  /* 90,552 */
#define PREP_TASKS (WB_TASKS + MASK_TASKS + BIAS_TASKS)

static __device__ __forceinline__ f32x4 mfma_bf16(bf16x8 a, bf16x8 b, f32x4 c) {
    return __builtin_amdgcn_mfma_f32_16x16x32_bf16(a, b, c, 0, 0, 0);
}

/* ---------------- fused prep: weights->bf16, mask->e^mask, bias->e^bias ---------------- */
__global__ __launch_bounds__(256) void prep_kernel(
    const float* __restrict__ wq, const float* __restrict__ wk,
    const float* __restrict__ wv, const float* __restrict__ pw,
    const float* __restrict__ mask, const float* __restrict__ rel_table,
    bf16_t* __restrict__ wb, bf16_t* __restrict__ mp, bf16_t* __restrict__ bp)
{
    for (int t = blockIdx.x * 256 + threadIdx.x; t < PREP_TASKS; t += 2048 * 256) {
        if (t < WB_TASKS) {
            int mat = t / 4608, off = (t % 4608) * 8;
            const float* src = (mat == 0) ? wq : ((mat == 1) ? wk : ((mat == 2) ? wv : pw));
            const float scale = (mat == 0) ? (0.17677669529663687f * LOG2E) : 1.0f;
            float4 f0 = *(const float4*)(src + off);
            float4 f1 = *(const float4*)(src + off + 4);
            bf16x8 o;
            o[0]=(bf16_t)(f0.x*scale); o[1]=(bf16_t)(f0.y*scale);
            o[2]=(bf16_t)(f0.z*scale); o[3]=(bf16_t)(f0.w*scale);
            o[4]=(bf16_t)(f1.x*scale); o[5]=(bf16_t)(f1.y*scale);
            o[6]=(bf16_t)(f1.z*scale); o[7]=(bf16_t)(f1.w*scale);
            *(bf16x8*)(wb + mat * 36864 + off) = o;
        } else if (t < WB_TASKS + MASK_TASKS) {
            int u = t - WB_TASKS;
            int row = u / MROW_CH, col = (u % MROW_CH) * 8;   /* row: w*343+r */
            const float* src = mask + (long)row * N_TOK;
            bf16x8 o;
            #pragma unroll
            for (int e = 0; e < 8; e++) {
                int j = col + e;
                float vv = 0.f;
                if (j < N_TOK) vv = __builtin_amdgcn_exp2f(src[j] * LOG2E);
                o[e] = (bf16_t)vv;
            }
            *(bf16x8*)(mp + (long)row * NP + col) = o;
        } else {
            int u = t - WB_TASKS - MASK_TASKS;
            int row = u / MROW_CH, col = (u % MROW_CH) * 8;   /* row: h*343+r */
            int h = row / N_TOK, r = row - h * N_TOK;
            int dr = r / 49, hr = (r / 7) % 7, wr = r % 7;
            bf16x8 o;
            #pragma unroll
            for (int e = 0; e < 8; e++) {
                int j = col + e;
                float vv = 0.f;
                if (j < N_TOK) {
                    int dj = j / 49, hj = (j / 7) % 7, wj = j % 7;
                    int idx = (dr - dj + 6) * 169 + (hr - hj + 6) * 13 + (wr - wj + 6);
                    vv = __builtin_amdgcn_exp2f(rel_table[idx * HEADS + h] * LOG2E);
                }
                o[e] = (bf16_t)vv;
            }
            *(bf16x8*)(bp + (long)row * NP + col) = o;
        }
    }
}

/* ---------------- QKV projection: R15 structure + depth-1 weight prefetch ----------------
   The 6 weight-fragment L2 loads heading each ct-iteration are issued one
   iteration AHEAD (register double-buffer, static indexing, clamped last
   iteration) so they overlap the previous iteration's 24 MFMAs. */
__global__ __launch_bounds__(256) void qkv_kernel(
    const float* __restrict__ x, const bf16_t* __restrict__ wb,
    bf16_t* __restrict__ qo, bf16_t* __restrict__ ko, bf16_t* __restrict__ vo)
{
    __shared__ __align__(16) bf16_t xs[64 * 200];
    const int tid = threadIdx.x;
    const long m0 = (long)blockIdx.x * 64;
    for (int e = tid; e < 3072; e += 256) {            /* 64 rows x 192 f32, as float4 */
        int flat = e * 4;
        int row = flat / 192, col = flat - row * 192;
        float4 f = *(const float4*)(x + m0 * 192 + flat);
        bf16_t* dst = &xs[row * 200 + col];
        dst[0] = (bf16_t)f.x; dst[1] = (bf16_t)f.y;
        dst[2] = (bf16_t)f.z; dst[3] = (bf16_t)f.w;
    }
    __syncthreads();
    const int wave = tid >> 6, lane = tid & 63;
    const int g = lane >> 4, c = lane & 15;

    /* prefetch fragments for first ct */
    bf16x8 cur[6];
    {
        const int ct0 = wave, mat0 = ct0 / 12, n00 = (ct0 % 12) * 16;
        const bf16_t* wrow0 = wb + mat0 * 36864 + (n00 + c) * 192 + g * 8;
        #pragma unroll
        for (int ks = 0; ks < 6; ks++) cur[ks] = *(const bf16x8*)(wrow0 + ks * 32);
    }
    #pragma unroll 1
    for (int ct = wave; ct < 36; ct += 4) {
        const int mat = ct / 12, n0 = (ct % 12) * 16;
        bf16_t* O = (mat == 0) ? qo : ((mat == 1) ? ko : vo);
        const int hh = n0 >> 5, dch = (n0 & 31) + g * 4;
        /* issue NEXT iteration's weight loads (clamped in-bounds) */
        const int ctn = (ct + 4 < 36) ? (ct + 4) : ct;
        const int matn = ctn / 12, n0n = (ctn % 12) * 16;
        const bf16_t* wrown = wb + matn * 36864 + (n0n + c) * 192 + g * 8;
        bf16x8 nxt[6];
        #pragma unroll
        for (int ks = 0; ks < 6; ks++) nxt[ks] = *(const bf16x8*)(wrown + ks * 32);
        #pragma unroll
        for (int mt = 0; mt < 4; mt++) {
            f32x4 acc = {0.f, 0.f, 0.f, 0.f};
            #pragma unroll
            for (int ks = 0; ks < 6; ks++) {
                bf16x8 a = *(const bf16x8*)&xs[(mt * 16 + c) * 200 + ks * 32 + g * 8];
                acc = mfma_bf16(cur[ks], a, acc);      /* swapped: reg dim = channel */
            }
            int m = (int)m0 + mt * 16 + c;             /* lane c = token */
            int bb = m / 343;                          /* magic-mul */
            int tok = m - bb * 343;
            bf16x4 o4;
            o4[0]=(bf16_t)acc[0]; o4[1]=(bf16_t)acc[1];
            o4[2]=(bf16_t)acc[2]; o4[3]=(bf16_t)acc[3];
            *(bf16x4*)(O + ((long)(bb * 6 + hh) * 343 + tok) * 32 + dch) = o4;
        }
        #pragma unroll
        for (int ks = 0; ks < 6; ks++) cur[ks] = nxt[ks];
    }
}

/* ---------------- fused attention per (batch, head) ----------------
   R13/R15/R18 PROVEN dual-QT (tri-QT regressed: VGPR 104 cost occupancy).
   Each wave processes q-tiles (qt, qt+4) sharing the K/V LDS reads. */
__global__ __launch_bounds__(256) void attn_kernel(
    const bf16_t* __restrict__ q, const bf16_t* __restrict__ k,
    const bf16_t* __restrict__ v, const bf16_t* __restrict__ maskp,
    const bf16_t* __restrict__ biasp, bf16_t* __restrict__ aout)
{
    __shared__ __align__(16) bf16_t K_lds[NP * 40];    /* permuted rows, padded stride */
    __shared__ __align__(16) bf16_t Vt_lds[HD * 360];  /* transposed V */
    const int f = blockIdx.x;                 /* 0..1535, bijective remap */
    const int xcd = f & 7;
    const int idx8 = f >> 3;                  /* 0..191 */
    const int pair = xcd * 48 + (idx8 >> 2);  /* 0..383 = w*6 + h */
    const int rep  = idx8 & 3;
    const int w = pair / 6, h = pair - (pair / 6) * 6;
    const int b = rep * 64 + w;
    const int tid = threadIdx.x;
    const bf16_t* kbase = k + (long)(b * 6 + h) * N_TOK * HD;
    const bf16_t* vbase = v + (long)(b * 6 + h) * N_TOK * HD;
    const bf16_t* qb    = q + (long)(b * 6 + h) * N_TOK * HD;

    /* stage K (linear source) with within-32 row permutation */
    for (int idx = tid; idx < 1408; idx += 256) {
        int j = idx >> 2, dcol = (idx & 3) * 8;
        int blk = j >> 5, w32 = j & 31;
        int gg = w32 >> 3, rem = w32 & 7, tt = rem >> 2, ii = rem & 3;
        int lr = blk * 32 + tt * 16 + gg * 4 + ii;
        bf16x8 val = {};
        if (j < N_TOK) val = *(const bf16x8*)(kbase + idx * 8);
        *(bf16x8*)&K_lds[lr * 40 + dcol] = val;
    }
    /* stage V transposed: Vt[d][j] */
    for (int idx = tid; idx < 1408; idx += 256) {
        int j = idx >> 2, dcol = (idx & 3) * 8;
        if (j < N_TOK) {
            bf16x8 val = *(const bf16x8*)(vbase + idx * 8);
            #pragma unroll
            for (int ii = 0; ii < 8; ii++) Vt_lds[(dcol + ii) * 360 + j] = val[ii];
        } else {
            #pragma unroll
            for (int ii = 0; ii < 8; ii++) Vt_lds[(dcol + ii) * 360 + j] = (bf16_t)0.f;
        }
    }
    __syncthreads();

    const int wave = tid >> 6, lane = tid & 63;
    const int g = lane >> 4, c = lane & 15;
    const bf16_t* mbase = maskp + (long)w * N_TOK * NP;
    const bf16_t* bbase = biasp + (long)h * N_TOK * NP;

    #pragma unroll 1
    for (int qt1 = wave; qt1 < 22; qt1 += 8) {
        const int qt2 = qt1 + 4;                       /* may be 22/23: clamped+guarded */
        const int rc1 = min(qt1 * 16 + c, N_TOK - 1);
        const int rc2 = min(qt2 * 16 + c, N_TOK - 1);
        bf16x8 qf1 = *(const bf16x8*)(qb + (long)rc1 * HD + g * 8);
        bf16x8 qf2 = *(const bf16x8*)(qb + (long)rc2 * HD + g * 8);
        const bf16_t* mrow1 = mbase + (long)rc1 * NP;
        const bf16_t* brow1 = bbase + (long)rc1 * NP;
        const bf16_t* mrow2 = mbase + (long)rc2 * NP;
        const bf16_t* brow2 = bbase + (long)rc2 * NP;
        f32x4 olo1 = {0.f,0.f,0.f,0.f}, ohi1 = {0.f,0.f,0.f,0.f};
        f32x4 olo2 = {0.f,0.f,0.f,0.f}, ohi2 = {0.f,0.f,0.f,0.f};
        float rs1 = 0.f, rs2 = 0.f;
        for (int jb = 0; jb < 11; jb++) {
            const int j0 = jb * 32 + g * 8;
            bf16x8 fm1 = *(const bf16x8*)(mrow1 + j0);
            bf16x8 fb1 = *(const bf16x8*)(brow1 + j0);
            bf16x8 fm2 = *(const bf16x8*)(mrow2 + j0);
            bf16x8 fb2 = *(const bf16x8*)(brow2 + j0);
            bf16x8 k0 = *(const bf16x8*)&K_lds[(jb * 32 + c) * 40 + g * 8];
            bf16x8 k1 = *(const bf16x8*)&K_lds[(jb * 32 + 16 + c) * 40 + g * 8];
            bf16x8 v0 = *(const bf16x8*)&Vt_lds[c * 360 + j0];
            bf16x8 v1 = *(const bf16x8*)&Vt_lds[(c + 16) * 360 + j0];
            const f32x4 z = {0.f,0.f,0.f,0.f};
            f32x4 s0a = mfma_bf16(k0, qf1, z);
            f32x4 s1a = mfma_bf16(k1, qf1, z);
            f32x4 s0b = mfma_bf16(k0, qf2, z);
            f32x4 s1b = mfma_bf16(k1, qf2, z);
            float p1[8], p2[8];
            #pragma unroll
            for (int e = 0; e < 4; e++) {
                p1[e]     = __builtin_amdgcn_exp2f(s0a[e]) * ((float)fm1[e]     * (float)fb1[e]);
                p1[4 + e] = __builtin_amdgcn_exp2f(s1a[e]) * ((float)fm1[4 + e] * (float)fb1[4 + e]);
                p2[e]     = __builtin_amdgcn_exp2f(s0b[e]) * ((float)fm2[e]     * (float)fb2[e]);
                p2[4 + e] = __builtin_amdgcn_exp2f(s1b[e]) * ((float)fm2[4 + e] * (float)fb2[4 + e]);
            }
            #pragma unroll
            for (int e = 0; e < 8; e++) { rs1 += p1[e]; rs2 += p2[e]; }
            bf16x8 pf1, pf2;
            #pragma unroll
            for (int e = 0; e < 8; e++) { pf1[e] = (bf16_t)p1[e]; pf2[e] = (bf16_t)p2[e]; }
            olo1 = mfma_bf16(pf1, v0, olo1);
            ohi1 = mfma_bf16(pf1, v1, ohi1);
            olo2 = mfma_bf16(pf2, v0, olo2);
            ohi2 = mfma_bf16(pf2, v1, ohi2);
        }
        rs1 += __shfl_xor(rs1, 16);
        rs1 += __shfl_xor(rs1, 32);
        rs2 += __shfl_xor(rs2, 16);
        rs2 += __shfl_xor(rs2, 32);
        #pragma unroll
        for (int i = 0; i < 4; i++) {
            int row1 = qt1 * 16 + g * 4 + i;
            if (row1 < N_TOK) {
                float inv = 1.f / __shfl(rs1, g * 4 + i);
                bf16_t* dst = aout + ((long)(b * 6 + h) * N_TOK + row1) * HD;
                dst[c]      = (bf16_t)(olo1[i] * inv);
                dst[c + 16] = (bf16_t)(ohi1[i] * inv);
            }
            int row2 = qt2 * 16 + g * 4 + i;
            if (row2 < N_TOK) {
                float inv = 1.f / __shfl(rs2, g * 4 + i);
                bf16_t* dst = aout + ((long)(b * 6 + h) * N_TOK + row2) * HD;
                dst[c]      = (bf16_t)(olo2[i] * inv);
                dst[c + 16] = (bf16_t)(ohi2[i] * inv);
            }
        }
    }
}

/* ---------------- output projection: R15-proven (swapped-operand epilogue) ---------------- */
__global__ __launch_bounds__(256) void proj_kernel(
    const bf16_t* __restrict__ A, const bf16_t* __restrict__ wb,
    const float* __restrict__ bias, float* __restrict__ out)
{
    __shared__ __align__(16) bf16_t xs[64 * 200];
    const int tid = threadIdx.x;
    const long m0 = (long)blockIdx.x * 64;
    for (int e = tid; e < 1536; e += 256) {           /* 64 rows x 24 chunks of 8 bf16 */
        int row = e / 24, col = (e % 24) * 8;
        int m = (int)m0 + row;
        int bb = m / 343;                             /* magic-mul */
        int tok = m - bb * 343;
        int hh = col >> 5, dd = col & 31;
        *(bf16x8*)&xs[row * 200 + col] =
            *(const bf16x8*)(A + ((long)(bb * 6 + hh) * 343 + tok) * 32 + dd);
    }
    __syncthreads();
    const int wave = tid >> 6, lane = tid & 63;
    const int g = lane >> 4, c = lane & 15;
    #pragma unroll 1
    for (int ct = wave; ct < 12; ct += 4) {
        const int n0 = ct * 16;
        const bf16_t* wrow = wb + 3 * 36864 + (n0 + c) * 192 + g * 8;
        bf16x8 bfrag[6];
        #pragma unroll
        for (int ks = 0; ks < 6; ks++) bfrag[ks] = *(const bf16x8*)(wrow + ks * 32);
        float4 bv4 = *(const float4*)(bias + n0 + g * 4);
        #pragma unroll
        for (int mt = 0; mt < 4; mt++) {
            f32x4 acc = {0.f, 0.f, 0.f, 0.f};
            #pragma unroll
            for (int ks = 0; ks < 6; ks++) {
                bf16x8 a = *(const bf16x8*)&xs[(mt * 16 + c) * 200 + ks * 32 + g * 8];
                acc = mfma_bf16(bfrag[ks], a, acc);    /* swapped: reg dim = channel */
            }
            long m = m0 + mt * 16 + c;                 /* lane c = token */
            float4 o;
            o.x = acc[0] + bv4.x; o.y = acc[1] + bv4.y;
            o.z = acc[2] + bv4.z; o.w = acc[3] + bv4.w;
            *(float4*)(out + m * 192 + n0 + g * 4) = o;
        }
    }
}

extern "C" void kernel_launch(void* const* d_in, const int* in_sizes, int n_in,
                              void* d_out, int out_size, void* d_ws, size_t ws_size,
                              hipStream_t stream)
{
    const float* x         = (const float*)d_in[0];
    const float* mask      = (const float*)d_in[1];
    const float* wq        = (const float*)d_in[2];
    const float* wk        = (const float*)d_in[3];
    const float* wv        = (const float*)d_in[4];
    const float* rel_table = (const float*)d_in[5];
    const float* proj_w    = (const float*)d_in[6];
    const float* proj_b    = (const float*)d_in[7];
    float* out = (float*)d_out;

    char* ws = (char*)d_ws;
    const size_t SZ = (size_t)MROWS * DIM * 2;          /* 33,718,272 B per bf16 tensor */
    bf16_t* q_ws  = (bf16_t*)(ws);
    bf16_t* k_ws  = (bf16_t*)(ws + SZ);
    bf16_t* v_ws  = (bf16_t*)(ws + 2 * SZ);
    bf16_t* a_ws  = (bf16_t*)(ws + 3 * SZ);
    bf16_t* mp_ws = (bf16_t*)(ws + 4 * SZ);
    bf16_t* bp_ws = (bf16_t*)(ws + 4 * SZ + (size_t)NW * N_TOK * NP * 2);
    bf16_t* wb_ws = (bf16_t*)(ws + 4 * SZ + (size_t)NW * N_TOK * NP * 2
                                 + (size_t)HEADS * N_TOK * NP * 2);

    hipLaunchKernelGGL(prep_kernel, dim3(2048), dim3(256), 0, stream,
                       wq, wk, wv, proj_w, mask, rel_table, wb_ws, mp_ws, bp_ws);
    hipLaunchKernelGGL(qkv_kernel, dim3(1372), dim3(256), 0, stream,
                       x, wb_ws, q_ws, k_ws, v_ws);
    hipLaunchKernelGGL(attn_kernel, dim3(BATCH * HEADS), dim3(256), 0, stream,
                       q_ws, k_ws, v_ws, mp_ws, bp_ws, a_ws);
    hipLaunchKernelGGL(proj_kernel, dim3(1372), dim3(256), 0, stream,
                       a_ws, wb_ws, proj_b, out);
}

// Round 21
// 194.919 us; speedup vs baseline: 1.0716x; 1.0716x over previous
//
#include <hip/hip_runtime.h>
#include <hip/hip_bf16.h>

typedef __bf16 bf16_t;
typedef __bf16 bf16x8 __attribute__((ext_vector_type(8)));
typedef __bf16 bf16x4 __attribute__((ext_vector_type(4)));
typedef float f32x4 __attribute__((ext_vector_type(4)));

#define N_TOK 343
#define NP    352
#define DIM   192
#define HEADS 6
#define HD    32
#define BATCH 256
#define NW    64
#define MROWS (BATCH * N_TOK)   /* 87808 = 1372 * 64 */
#define LOG2E 1.4426950408889634f

/* prep task-space segmentation */
#define WB_TASKS   18432                      /* 4 mats x 4608 8-chunks */
#define MROW_CH    44                         /* 352/8 chunks per row */
#define MASK_TASKS (NW * N_TOK * MROW_CH)     /* 965,888 */
#define BIAS_TASKS (HEADS * N_TOK * MROW_CH)  /* 90,552 */
#define PREP_TASKS (WB_TASKS + MASK_TASKS + BIAS_TASKS)

static __device__ __forceinline__ f32x4 mfma_bf16(bf16x8 a, bf16x8 b, f32x4 c) {
    return __builtin_amdgcn_mfma_f32_16x16x32_bf16(a, b, c, 0, 0, 0);
}

/* ---------------- fused prep: weights->bf16, mask->e^mask, bias->e^bias ---------------- */
__global__ __launch_bounds__(256) void prep_kernel(
    const float* __restrict__ wq, const float* __restrict__ wk,
    const float* __restrict__ wv, const float* __restrict__ pw,
    const float* __restrict__ mask, const float* __restrict__ rel_table,
    bf16_t* __restrict__ wb, bf16_t* __restrict__ mp, bf16_t* __restrict__ bp)
{
    for (int t = blockIdx.x * 256 + threadIdx.x; t < PREP_TASKS; t += 2048 * 256) {
        if (t < WB_TASKS) {
            int mat = t / 4608, off = (t % 4608) * 8;
            const float* src = (mat == 0) ? wq : ((mat == 1) ? wk : ((mat == 2) ? wv : pw));
            const float scale = (mat == 0) ? (0.17677669529663687f * LOG2E) : 1.0f;
            float4 f0 = *(const float4*)(src + off);
            float4 f1 = *(const float4*)(src + off + 4);
            bf16x8 o;
            o[0]=(bf16_t)(f0.x*scale); o[1]=(bf16_t)(f0.y*scale);
            o[2]=(bf16_t)(f0.z*scale); o[3]=(bf16_t)(f0.w*scale);
            o[4]=(bf16_t)(f1.x*scale); o[5]=(bf16_t)(f1.y*scale);
            o[6]=(bf16_t)(f1.z*scale); o[7]=(bf16_t)(f1.w*scale);
            *(bf16x8*)(wb + mat * 36864 + off) = o;
        } else if (t < WB_TASKS + MASK_TASKS) {
            int u = t - WB_TASKS;
            int row = u / MROW_CH, col = (u % MROW_CH) * 8;   /* row: w*343+r */
            const float* src = mask + (long)row * N_TOK;
            bf16x8 o;
            #pragma unroll
            for (int e = 0; e < 8; e++) {
                int j = col + e;
                float vv = 0.f;
                if (j < N_TOK) vv = __builtin_amdgcn_exp2f(src[j] * LOG2E);
                o[e] = (bf16_t)vv;
            }
            *(bf16x8*)(mp + (long)row * NP + col) = o;
        } else {
            int u = t - WB_TASKS - MASK_TASKS;
            int row = u / MROW_CH, col = (u % MROW_CH) * 8;   /* row: h*343+r */
            int h = row / N_TOK, r = row - h * N_TOK;
            int dr = r / 49, hr = (r / 7) % 7, wr = r % 7;
            bf16x8 o;
            #pragma unroll
            for (int e = 0; e < 8; e++) {
                int j = col + e;
                float vv = 0.f;
                if (j < N_TOK) {
                    int dj = j / 49, hj = (j / 7) % 7, wj = j % 7;
                    int idx = (dr - dj + 6) * 169 + (hr - hj + 6) * 13 + (wr - wj + 6);
                    vv = __builtin_amdgcn_exp2f(rel_table[idx * HEADS + h] * LOG2E);
                }
                o[e] = (bf16_t)vv;
            }
            *(bf16x8*)(bp + (long)row * NP + col) = o;
        }
    }
}

/* ---------------- QKV projection: R15-proven (swapped-operand epilogue) ---------------- */
__global__ __launch_bounds__(256) void qkv_kernel(
    const float* __restrict__ x, const bf16_t* __restrict__ wb,
    bf16_t* __restrict__ qo, bf16_t* __restrict__ ko, bf16_t* __restrict__ vo)
{
    __shared__ __align__(16) bf16_t xs[64 * 200];
    const int tid = threadIdx.x;
    const long m0 = (long)blockIdx.x * 64;
    for (int e = tid; e < 3072; e += 256) {            /* 64 rows x 192 f32, as float4 */
        int flat = e * 4;
        int row = flat / 192, col = flat - row * 192;
        float4 f = *(const float4*)(x + m0 * 192 + flat);
        bf16_t* dst = &xs[row * 200 + col];
        dst[0] = (bf16_t)f.x; dst[1] = (bf16_t)f.y;
        dst[2] = (bf16_t)f.z; dst[3] = (bf16_t)f.w;
    }
    __syncthreads();
    const int wave = tid >> 6, lane = tid & 63;
    const int g = lane >> 4, c = lane & 15;
    #pragma unroll 1
    for (int ct = wave; ct < 36; ct += 4) {
        const int mat = ct / 12, n0 = (ct % 12) * 16;
        bf16_t* O = (mat == 0) ? qo : ((mat == 1) ? ko : vo);
        const int hh = n0 >> 5, dch = (n0 & 31) + g * 4;
        const bf16_t* wrow = wb + mat * 36864 + (n0 + c) * 192 + g * 8;
        bf16x8 bfrag[6];
        #pragma unroll
        for (int ks = 0; ks < 6; ks++) bfrag[ks] = *(const bf16x8*)(wrow + ks * 32);
        #pragma unroll
        for (int mt = 0; mt < 4; mt++) {
            f32x4 acc = {0.f, 0.f, 0.f, 0.f};
            #pragma unroll
            for (int ks = 0; ks < 6; ks++) {
                bf16x8 a = *(const bf16x8*)&xs[(mt * 16 + c) * 200 + ks * 32 + g * 8];
                acc = mfma_bf16(bfrag[ks], a, acc);    /* swapped: reg dim = channel */
            }
            int m = (int)m0 + mt * 16 + c;             /* lane c = token */
            int bb = m / 343;                          /* magic-mul */
            int tok = m - bb * 343;
            bf16x4 o4;
            o4[0]=(bf16_t)acc[0]; o4[1]=(bf16_t)acc[1];
            o4[2]=(bf16_t)acc[2]; o4[3]=(bf16_t)acc[3];
            *(bf16x4*)(O + ((long)(bb * 6 + hh) * 343 + tok) * 32 + dch) = o4;
        }
    }
}

/* ---------------- fused attention per (batch, head) ----------------
   R13/R15 PROVEN version. Dual-QT: each wave processes q-tiles (qt, qt+4)
   sharing the K/V LDS reads -> 2 independent dep chains per step. */
__global__ __launch_bounds__(256) void attn_kernel(
    const bf16_t* __restrict__ q, const bf16_t* __restrict__ k,
    const bf16_t* __restrict__ v, const bf16_t* __restrict__ maskp,
    const bf16_t* __restrict__ biasp, bf16_t* __restrict__ aout)
{
    __shared__ __align__(16) bf16_t K_lds[NP * 40];    /* permuted rows, padded stride */
    __shared__ __align__(16) bf16_t Vt_lds[HD * 360];  /* transposed V */
    const int f = blockIdx.x;                 /* 0..1535, bijective remap */
    const int xcd = f & 7;
    const int idx8 = f >> 3;                  /* 0..191 */
    const int pair = xcd * 48 + (idx8 >> 2);  /* 0..383 = w*6 + h */
    const int rep  = idx8 & 3;
    const int w = pair / 6, h = pair - (pair / 6) * 6;
    const int b = rep * 64 + w;
    const int tid = threadIdx.x;
    const bf16_t* kbase = k + (long)(b * 6 + h) * N_TOK * HD;
    const bf16_t* vbase = v + (long)(b * 6 + h) * N_TOK * HD;
    const bf16_t* qb    = q + (long)(b * 6 + h) * N_TOK * HD;

    /* stage K (linear source) with within-32 row permutation */
    for (int idx = tid; idx < 1408; idx += 256) {
        int j = idx >> 2, dcol = (idx & 3) * 8;
        int blk = j >> 5, w32 = j & 31;
        int gg = w32 >> 3, rem = w32 & 7, tt = rem >> 2, ii = rem & 3;
        int lr = blk * 32 + tt * 16 + gg * 4 + ii;
        bf16x8 val = {};
        if (j < N_TOK) val = *(const bf16x8*)(kbase + idx * 8);
        *(bf16x8*)&K_lds[lr * 40 + dcol] = val;
    }
    /* stage V transposed: Vt[d][j] */
    for (int idx = tid; idx < 1408; idx += 256) {
        int j = idx >> 2, dcol = (idx & 3) * 8;
        if (j < N_TOK) {
            bf16x8 val = *(const bf16x8*)(vbase + idx * 8);
            #pragma unroll
            for (int ii = 0; ii < 8; ii++) Vt_lds[(dcol + ii) * 360 + j] = val[ii];
        } else {
            #pragma unroll
            for (int ii = 0; ii < 8; ii++) Vt_lds[(dcol + ii) * 360 + j] = (bf16_t)0.f;
        }
    }
    __syncthreads();

    const int wave = tid >> 6, lane = tid & 63;
    const int g = lane >> 4, c = lane & 15;
    const bf16_t* mbase = maskp + (long)w * N_TOK * NP;
    const bf16_t* bbase = biasp + (long)h * N_TOK * NP;

    #pragma unroll 1
    for (int qt1 = wave; qt1 < 22; qt1 += 8) {
        const int qt2 = qt1 + 4;                       /* may be 22/23: clamped+guarded */
        const int rc1 = min(qt1 * 16 + c, N_TOK - 1);
        const int rc2 = min(qt2 * 16 + c, N_TOK - 1);
        bf16x8 qf1 = *(const bf16x8*)(qb + (long)rc1 * HD + g * 8);
        bf16x8 qf2 = *(const bf16x8*)(qb + (long)rc2 * HD + g * 8);
        const bf16_t* mrow1 = mbase + (long)rc1 * NP;
        const bf16_t* brow1 = bbase + (long)rc1 * NP;
        const bf16_t* mrow2 = mbase + (long)rc2 * NP;
        const bf16_t* brow2 = bbase + (long)rc2 * NP;
        f32x4 olo1 = {0.f,0.f,0.f,0.f}, ohi1 = {0.f,0.f,0.f,0.f};
        f32x4 olo2 = {0.f,0.f,0.f,0.f}, ohi2 = {0.f,0.f,0.f,0.f};
        float rs1 = 0.f, rs2 = 0.f;
        for (int jb = 0; jb < 11; jb++) {
            const int j0 = jb * 32 + g * 8;
            bf16x8 fm1 = *(const bf16x8*)(mrow1 + j0);
            bf16x8 fb1 = *(const bf16x8*)(brow1 + j0);
            bf16x8 fm2 = *(const bf16x8*)(mrow2 + j0);
            bf16x8 fb2 = *(const bf16x8*)(brow2 + j0);
            bf16x8 k0 = *(const bf16x8*)&K_lds[(jb * 32 + c) * 40 + g * 8];
            bf16x8 k1 = *(const bf16x8*)&K_lds[(jb * 32 + 16 + c) * 40 + g * 8];
            bf16x8 v0 = *(const bf16x8*)&Vt_lds[c * 360 + j0];
            bf16x8 v1 = *(const bf16x8*)&Vt_lds[(c + 16) * 360 + j0];
            const f32x4 z = {0.f,0.f,0.f,0.f};
            f32x4 s0a = mfma_bf16(k0, qf1, z);
            f32x4 s1a = mfma_bf16(k1, qf1, z);
            f32x4 s0b = mfma_bf16(k0, qf2, z);
            f32x4 s1b = mfma_bf16(k1, qf2, z);
            float p1[8], p2[8];
            #pragma unroll
            for (int e = 0; e < 4; e++) {
                p1[e]     = __builtin_amdgcn_exp2f(s0a[e]) * ((float)fm1[e]     * (float)fb1[e]);
                p1[4 + e] = __builtin_amdgcn_exp2f(s1a[e]) * ((float)fm1[4 + e] * (float)fb1[4 + e]);
                p2[e]     = __builtin_amdgcn_exp2f(s0b[e]) * ((float)fm2[e]     * (float)fb2[e]);
                p2[4 + e] = __builtin_amdgcn_exp2f(s1b[e]) * ((float)fm2[4 + e] * (float)fb2[4 + e]);
            }
            #pragma unroll
            for (int e = 0; e < 8; e++) { rs1 += p1[e]; rs2 += p2[e]; }
            bf16x8 pf1, pf2;
            #pragma unroll
            for (int e = 0; e < 8; e++) { pf1[e] = (bf16_t)p1[e]; pf2[e] = (bf16_t)p2[e]; }
            olo1 = mfma_bf16(pf1, v0, olo1);
            ohi1 = mfma_bf16(pf1, v1, ohi1);
            olo2 = mfma_bf16(pf2, v0, olo2);
            ohi2 = mfma_bf16(pf2, v1, ohi2);
        }
        rs1 += __shfl_xor(rs1, 16);
        rs1 += __shfl_xor(rs1, 32);
        rs2 += __shfl_xor(rs2, 16);
        rs2 += __shfl_xor(rs2, 32);
        #pragma unroll
        for (int i = 0; i < 4; i++) {
            int row1 = qt1 * 16 + g * 4 + i;
            if (row1 < N_TOK) {
                float inv = 1.f / __shfl(rs1, g * 4 + i);
                bf16_t* dst = aout + ((long)(b * 6 + h) * N_TOK + row1) * HD;
                dst[c]      = (bf16_t)(olo1[i] * inv);
                dst[c + 16] = (bf16_t)(ohi1[i] * inv);
            }
            int row2 = qt2 * 16 + g * 4 + i;
            if (row2 < N_TOK) {
                float inv = 1.f / __shfl(rs2, g * 4 + i);
                bf16_t* dst = aout + ((long)(b * 6 + h) * N_TOK + row2) * HD;
                dst[c]      = (bf16_t)(olo2[i] * inv);
                dst[c + 16] = (bf16_t)(ohi2[i] * inv);
            }
        }
    }
}

/* ---------------- output projection: R15-proven (swapped-operand epilogue) ---------------- */
__global__ __launch_bounds__(256) void proj_kernel(
    const bf16_t* __restrict__ A, const bf16_t* __restrict__ wb,
    const float* __restrict__ bias, float* __restrict__ out)
{
    __shared__ __align__(16) bf16_t xs[64 * 200];
    const int tid = threadIdx.x;
    const long m0 = (long)blockIdx.x * 64;
    for (int e = tid; e < 1536; e += 256) {           /* 64 rows x 24 chunks of 8 bf16 */
        int row = e / 24, col = (e % 24) * 8;
        int m = (int)m0 + row;
        int bb = m / 343;                             /* magic-mul */
        int tok = m - bb * 343;
        int hh = col >> 5, dd = col & 31;
        *(bf16x8*)&xs[row * 200 + col] =
            *(const bf16x8*)(A + ((long)(bb * 6 + hh) * 343 + tok) * 32 + dd);
    }
    __syncthreads();
    const int wave = tid >> 6, lane = tid & 63;
    const int g = lane >> 4, c = lane & 15;
    #pragma unroll 1
    for (int ct = wave; ct < 12; ct += 4) {
        const int n0 = ct * 16;
        const bf16_t* wrow = wb + 3 * 36864 + (n0 + c) * 192 + g * 8;
        bf16x8 bfrag[6];
        #pragma unroll
        for (int ks = 0; ks < 6; ks++) bfrag[ks] = *(const bf16x8*)(wrow + ks * 32);
        float4 bv4 = *(const float4*)(bias + n0 + g * 4);
        #pragma unroll
        for (int mt = 0; mt < 4; mt++) {
            f32x4 acc = {0.f, 0.f, 0.f, 0.f};
            #pragma unroll
            for (int ks = 0; ks < 6; ks++) {
                bf16x8 a = *(const bf16x8*)&xs[(mt * 16 + c) * 200 + ks * 32 + g * 8];
                acc = mfma_bf16(bfrag[ks], a, acc);    /* swapped: reg dim = channel */
            }
            long m = m0 + mt * 16 + c;                 /* lane c = token */
            float4 o;
            o.x = acc[0] + bv4.x; o.y = acc[1] + bv4.y;
            o.z = acc[2] + bv4.z; o.w = acc[3] + bv4.w;
            *(float4*)(out + m * 192 + n0 + g * 4) = o;
        }
    }
}

extern "C" void kernel_launch(void* const* d_in, const int* in_sizes, int n_in,
                              void* d_out, int out_size, void* d_ws, size_t ws_size,
                              hipStream_t stream)
{
    const float* x         = (const float*)d_in[0];
    const float* mask      = (const float*)d_in[1];
    const float* wq        = (const float*)d_in[2];
    const float* wk        = (const float*)d_in[3];
    const float* wv        = (const float*)d_in[4];
    const float* rel_table = (const float*)d_in[5];
    const float* proj_w    = (const float*)d_in[6];
    const float* proj_b    = (const float*)d_in[7];
    float* out = (float*)d_out;

    char* ws = (char*)d_ws;
    const size_t SZ = (size_t)MROWS * DIM * 2;          /* 33,718,272 B per bf16 tensor */
    bf16_t* q_ws  = (bf16_t*)(ws);
    bf16_t* k_ws  = (bf16_t*)(ws + SZ);
    bf16_t* v_ws  = (bf16_t*)(ws + 2 * SZ);
    bf16_t* a_ws  = (bf16_t*)(ws + 3 * SZ);
    bf16_t* mp_ws = (bf16_t*)(ws + 4 * SZ);
    bf16_t* bp_ws = (bf16_t*)(ws + 4 * SZ + (size_t)NW * N_TOK * NP * 2);
    bf16_t* wb_ws = (bf16_t*)(ws + 4 * SZ + (size_t)NW * N_TOK * NP * 2
                                 + (size_t)HEADS * N_TOK * NP * 2);

    hipLaunchKernelGGL(prep_kernel, dim3(2048), dim3(256), 0, stream,
                       wq, wk, wv, proj_w, mask, rel_table, wb_ws, mp_ws, bp_ws);
    hipLaunchKernelGGL(qkv_kernel, dim3(1372), dim3(256), 0, stream,
                       x, wb_ws, q_ws, k_ws, v_ws);
    hipLaunchKernelGGL(attn_kernel, dim3(BATCH * HEADS), dim3(256), 0, stream,
                       q_ws, k_ws, v_ws, mp_ws, bp_ws, a_ws);
    hipLaunchKernelGGL(proj_kernel, dim3(1372), dim3(256), 0, stream,
                       a_ws, wb_ws, proj_b, out);
}